// Round 7
// baseline (583.149 us; speedup 1.0000x reference)
//
#include <hip/hip_runtime.h>
#include <math.h>

#define KSLOTS 8
#define PN     131072
#define LOC_RATIO 0.5714285714285714f
#define INV2048 4.8828125e-4f
#define RPS    76      // row-pair stride (dwords): 76 mod 32 = 12 -> 2-way-free reads AND writes

typedef _Float16 f16x8 __attribute__((ext_vector_type(8)));
typedef __fp16 pk16x2 __attribute__((ext_vector_type(2)));
typedef float floatx4 __attribute__((ext_vector_type(4)));
typedef int iv2 __attribute__((ext_vector_type(2)));
union F4H8 { int4 i; f16x8 h; };
union PK2I { pk16x2 h; int i; };

#define MFMA(A_,B_,C_) __builtin_amdgcn_mfma_f32_16x16x32_f16(A_,B_,C_,0,0,0)

// ---- B-fragment pair bases (each pair = bh,bl slots; slot = e*2+term) ----
#define EB_B0   0
#define EB_B1   4
#define EB_B2   12
#define EB_A0Q  20
#define EB_A0H  24
#define EB_A1   32
#define EB_A2   40
#define EB_LAT  48
#define EB_C0   58
// frag region: 60 pairs * 2 slots * 64 lanes * 4 dw = 30720 dwords
#define WS_ZB0  30720   // [8][64] f32
#define WS_ZA0  31232
#define WS_BST  31744   // b1@0 b2@64 a1@128 a2@192 latsh@256(80) c0@336(16)
#define WS_W32  32096   // wb0_col32[64], wa0_col32[64]

// ---- output layout (float offsets) ----
#define OFF_RAWS     0
#define OFF_MASKED   524288
#define OFF_UNMASK   4718592
#define OFF_MASKS    8912896

// ---- per-wave LDS map (dwords), row = 2480 ----
#define L_AH   0
#define L_AL   608
#define L_QH   1216
#define L_QL   1824
#define L_Q32  2432
#define L_OUTS 2448
#define L_SIG  2464
#define L_CC   1216
#define LROW   2480

// ============================ prep kernel ============================
__global__ void prep_kernel(const float* __restrict__ z_slots,
                            const float* __restrict__ w_b0, const float* __restrict__ b_b0,
                            const float* __restrict__ w_b1, const float* __restrict__ b_b1,
                            const float* __restrict__ w_b2, const float* __restrict__ b_b2,
                            const float* __restrict__ w_a0, const float* __restrict__ b_a0,
                            const float* __restrict__ w_a1, const float* __restrict__ b_a1,
                            const float* __restrict__ w_a2, const float* __restrict__ b_a2,
                            const float* __restrict__ w_lat, const float* __restrict__ b_lat,
                            const float* __restrict__ w_sh, const float* __restrict__ b_sh,
                            const float* __restrict__ w_c0, const float* __restrict__ b_c0,
                            float* __restrict__ ws) {
    const int tid = blockIdx.x * blockDim.x + threadIdx.x;
    if (tid < 7680) {
        const int lane = tid & 63;
        const int term = (tid >> 6) & 1;
        const int e    = tid >> 7;         // 0..59
        int u, nt, ks;
        if      (e < 4)  { u = 0; nt = e;            ks = 0; }
        else if (e < 12) { u = 1; nt = (e-4)  >> 1;  ks = (e-4)  & 1; }
        else if (e < 20) { u = 2; nt = (e-12) >> 1;  ks = (e-12) & 1; }
        else if (e < 24) { u = 3; nt = e - 20;       ks = 0; }
        else if (e < 32) { u = 4; nt = (e-24) >> 1;  ks = (e-24) & 1; }
        else if (e < 40) { u = 5; nt = (e-32) >> 1;  ks = (e-32) & 1; }
        else if (e < 48) { u = 6; nt = (e-40) >> 1;  ks = (e-40) & 1; }
        else if (e < 58) { u = 7; nt = (e-48) >> 1;  ks = (e-48) & 1; }
        else             { u = 8; nt = 0;            ks = e - 58; }
        const int jo = nt * 16 + (lane & 15);
        const int quad = lane >> 4;
        f16x8 frag;
#pragma unroll
        for (int j = 0; j < 8; ++j) {
            const int k = ks * 32 + quad * 8 + j;
            float w = 0.0f;
            switch (u) {
                case 0: w = w_b0[jo * 97 + k]; break;          // k<32
                case 1: w = w_b1[jo * 64 + k]; break;
                case 2: w = w_b2[jo * 64 + k]; break;
                case 3: w = w_a0[jo * 161 + k]; break;         // k<32
                case 4: w = w_a0[jo * 161 + 97 + k]; break;
                case 5: w = w_a1[jo * 64 + k]; break;
                case 6: w = w_a2[jo * 64 + k]; break;
                case 7: w = (jo < 64) ? w_lat[jo * 64 + k]
                          : ((jo == 64) ? w_sh[k] : 0.0f); break;
                default: w = w_c0[jo * 64 + k]; break;
            }
            const _Float16 hi = (_Float16)w;
            frag[j] = (term == 0) ? hi : (_Float16)((w - (float)hi) * 2048.0f);
        }
        ((f16x8*)ws)[tid] = frag;
    } else if (tid < 8192) {
        const int idx = tid - 7680;            // 0..511
        const int k = idx >> 6, j = idx & 63;
        float s0 = b_b0[j], s1 = b_a0[j];
        for (int i = 0; i < 64; ++i) {
            const float zv = z_slots[k * 64 + i];
            s0 = fmaf(w_b0[j * 97 + 33 + i], zv, s0);
            s1 = fmaf(w_a0[j * 161 + 33 + i], zv, s1);
        }
        ws[WS_ZB0 + idx] = s0;
        ws[WS_ZA0 + idx] = s1;
    } else if (tid < 8544) {
        const int idx = tid - 8192;            // 0..351
        float v;
        if      (idx < 64)  v = b_b1[idx];
        else if (idx < 128) v = b_b2[idx - 64];
        else if (idx < 192) v = b_a1[idx - 128];
        else if (idx < 256) v = b_a2[idx - 192];
        else if (idx < 336) { const int j = idx - 256; v = (j < 64) ? b_lat[j] : ((j == 64) ? b_sh[0] : 0.0f); }
        else                v = b_c0[idx - 336];
        ws[WS_BST + idx] = v;
    } else if (tid < 8672) {
        const int idx = tid - 8544;            // 0..127
        const int j = idx & 63;
        ws[WS_W32 + idx] = (idx < 64) ? w_b0[j * 97 + 32] : w_a0[j * 161 + 32];
    }
}

// ============================ device helpers ============================
__device__ __forceinline__ iv2 ldv2(const int* p) {
    return *(const volatile iv2*)p;   // volatile: keep as ds_read_b64 (2-way free), don't merge to b128 (4-way)
}

__device__ __forceinline__ f16x8 rdfragP(const int* plane, int addr, unsigned sel) {
    const iv2 a0 = ldv2(plane + addr);
    const iv2 a1 = ldv2(plane + addr + 2);
    const iv2 a2 = ldv2(plane + addr + 4);
    const iv2 a3 = ldv2(plane + addr + 6);
    F4H8 u;
    u.i.x = __builtin_amdgcn_perm(a0.y, a0.x, sel);
    u.i.y = __builtin_amdgcn_perm(a1.y, a1.x, sel);
    u.i.z = __builtin_amdgcn_perm(a2.y, a2.x, sel);
    u.i.w = __builtin_amdgcn_perm(a3.y, a3.x, sel);
    return u.h;
}

__device__ __forceinline__ f16x8 ldB(const int* ws_i, int slot, int lane) {
    F4H8 u;
    u.i = ((const int4*)ws_i)[slot * 64 + lane];
    return u.h;
}

__device__ __forceinline__ int pkrtz_i(float a, float b) {
    PK2I u;
    u.h = __builtin_amdgcn_cvt_pkrtz(a, b);
    return u.i;
}

__device__ __forceinline__ void st_split(int* AHw, int* ALw, int addr, floatx4 v) {
    const PK2I h01 = { __builtin_amdgcn_cvt_pkrtz(v[0], v[1]) };
    const PK2I h23 = { __builtin_amdgcn_cvt_pkrtz(v[2], v[3]) };
    const float f0 = (float)h01.h.x, f1 = (float)h01.h.y;
    const float f2 = (float)h23.h.x, f3 = (float)h23.h.y;
    AHw[addr]       = h01.i;
    AHw[addr + RPS] = h23.i;
    ALw[addr]       = pkrtz_i((v[0]-f0)*2048.f, (v[1]-f1)*2048.f);
    ALw[addr + RPS] = pkrtz_i((v[2]-f2)*2048.f, (v[3]-f3)*2048.f);
}

__device__ __forceinline__ void st_hi(int* AHw, int addr, floatx4 v) {
    AHw[addr]       = pkrtz_i(v[0], v[1]);
    AHw[addr + RPS] = pkrtz_i(v[2], v[3]);
}

__device__ __forceinline__ void st_pk16(int* QHw, int* QLw, int rp, int halfsel, int feat, float v) {
    const _Float16 h = (_Float16)v;
    const float hf = (float)h;
    const _Float16 l = (_Float16)((v - hf) * 2048.0f);
    ((unsigned short*)QHw)[(rp * RPS + feat) * 2 + halfsel] = __builtin_bit_cast(unsigned short, h);
    ((unsigned short*)QLw)[(rp * RPS + feat) * 2 + halfsel] = __builtin_bit_cast(unsigned short, l);
}

// ============================ main kernel ============================
__global__ __launch_bounds__(256, 4)
void fg_kernel(const float* __restrict__ coor_in,
               const float* __restrict__ fg_transform,
               const float* __restrict__ fg_slot_pos,
               const float* __restrict__ w_c1, const float* __restrict__ b_c1,
               const float* __restrict__ ws,
               float* __restrict__ out) {
    __shared__ int LB[4][LROW];
    const int lane = threadIdx.x & 63;
    const int wv   = threadIdx.x >> 6;
    const int tile = blockIdx.x * 4 + wv;
    const int kk = tile >> 13;            // 8192 tiles per slot
    const int p0 = (tile & 8191) << 4;

    int* AHw = LB[wv] + L_AH;
    int* ALw = LB[wv] + L_AL;
    int* QHw = LB[wv] + L_QH;
    int* QLw = LB[wv] + L_QL;
    float* Q32w  = (float*)(LB[wv] + L_Q32);
    float* OUTSw = (float*)(LB[wv] + L_OUTS);
    float* SIGw  = (float*)(LB[wv] + L_SIG);
    float* CCw   = (float*)(LB[wv] + L_CC);   // overlays QH (Q dead after a0)

    const int* ws_i = (const int*)ws;
    const int n = lane & 15, quad = lane >> 4;
    const unsigned sel = (n & 1) ? 0x07060302u : 0x05040100u;
    const int rdA = (n >> 1) * RPS + quad * 8;
    const int wrA = (2 * quad) * RPS + n;

    // ---- phase 0: embedding, non-divergent (role = quad, point = n) ----
    {
        const int p = n;
        const int role = quad;
        const long idx3 = ((long)kk * PN + p0 + p) * 3;
        const float x = coor_in[idx3 + 0];
        const float y = coor_in[idx3 + 1];
        const float zc = coor_in[idx3 + 2];
        const float T00 = fg_transform[0], T01 = fg_transform[1], T02 = fg_transform[2];
        const float T10 = fg_transform[3], T11 = fg_transform[4], T12 = fg_transform[5];
        const float T20 = fg_transform[6], T21 = fg_transform[7], T22 = fg_transform[8];
        if (role < 3) {
            const float px = fg_slot_pos[kk*3+0], py = fg_slot_pos[kk*3+1], pz = fg_slot_pos[kk*3+2];
            const float rx = x - px, ry = y - py, rz = zc - pz;
            const float cx = T00*rx + T01*ry + T02*rz;
            const float cy = T10*rx + T11*ry + T12*rz;
            const float cz = T20*rx + T21*ry + T22*rz;
            const float c = (role == 0) ? cx : ((role == 1) ? cy : cz);
            const int rp = p >> 1;
            const int hs = p & 1;
            st_pk16(QHw, QLw, rp, hs, role, c);
            const float rev = c * 0.15915494309189535f;
            const float fr = rev - floorf(rev);
            float s  = __builtin_amdgcn_sinf(fr);
            float co = __builtin_amdgcn_cosf(fr);
#pragma unroll
            for (int l = 0; l < 5; ++l) {
                st_pk16(QHw, QLw, rp, hs, 3 + 6*l + role, s);
                if (l == 4 && role == 2) {
                    Q32w[p] = co;                       // q[32] = cos(16 z), fp32
                } else {
                    st_pk16(QHw, QLw, rp, hs, 6 + 6*l + role, co);
                }
                if (l < 4) {
                    const float t = s * co;
                    const float s2 = s * s;
                    co = fmaf(-2.0f, s2, 1.0f);
                    s  = t + t;
                }
            }
        } else {
            const float o0 = T00*x + T01*y + T02*zc;
            const float o1 = T10*x + T11*y + T12*zc;
            const float o2 = T20*x + T21*y + T22*zc;
            const bool outs = (fabsf(o0) > LOC_RATIO) || (fabsf(o1) > LOC_RATIO) || (fabsf(o2) > LOC_RATIO);
            OUTSw[p] = outs ? 1.0f : 0.0f;
        }
    }

    // ---- q fragments (K=32, registers, reused by b0 and a0) ----
    const f16x8 qh0 = rdfragP(QHw, rdA, sel);
    const f16x8 ql0 = rdfragP(QLw, rdA, sel);
    floatx4 q32v;
#pragma unroll
    for (int r = 0; r < 4; ++r) q32v[r] = Q32w[quad * 4 + r];

    // ---- b0: q(K=32) + rank-1 q32 ----
    {
        const float* zb0 = ws + WS_ZB0 + kk * 64;
        const float* w32p = ws + WS_W32;
#pragma unroll
        for (int nt = 0; nt < 4; ++nt) {
            const float bv = zb0[nt * 16 + n];
            const float w32 = w32p[nt * 16 + n];
            floatx4 acc = {bv, bv, bv, bv};
            floatx4 am  = {0.f, 0.f, 0.f, 0.f};
            const int e = EB_B0 + nt;
            const f16x8 bh = ldB(ws_i, e*2+0, lane);
            const f16x8 bl = ldB(ws_i, e*2+1, lane);
            acc = MFMA(qh0, bh, acc); am = MFMA(qh0, bl, am); am = MFMA(ql0, bh, am);
            floatx4 v;
#pragma unroll
            for (int r = 0; r < 4; ++r) {
                float t = fmaf(am[r], INV2048, acc[r]);
                t = fmaf(w32, q32v[r], t);
                v[r] = fmaxf(t, 0.0f);
            }
            st_split(AHw, ALw, wrA + nt * 16, v);
        }
    }

    // ---- generic 64->64 hidden units ----
    f16x8 h0, l0, h1, l1;
#define RD_A() do { \
        h0 = rdfragP(AHw, rdA, sel);      l0 = rdfragP(ALw, rdA, sel); \
        h1 = rdfragP(AHw, rdA + 32, sel); l1 = rdfragP(ALw, rdA + 32, sel); \
    } while (0)

#define UNIT64(EBASE, BIASP, RELU) do { \
        const float* _b = (BIASP); \
        _Pragma("unroll") \
        for (int nt = 0; nt < 4; ++nt) { \
            const float bv = _b[nt * 16 + n]; \
            floatx4 acc = {bv, bv, bv, bv}; \
            floatx4 am  = {0.f, 0.f, 0.f, 0.f}; \
            const int e0 = (EBASE) + nt * 2; \
            const f16x8 bh0 = ldB(ws_i, e0*2+0, lane); \
            const f16x8 bl0 = ldB(ws_i, e0*2+1, lane); \
            const f16x8 bh1 = ldB(ws_i, e0*2+2, lane); \
            const f16x8 bl1 = ldB(ws_i, e0*2+3, lane); \
            acc = MFMA(h0, bh0, acc); am = MFMA(h0, bl0, am); am = MFMA(l0, bh0, am); \
            acc = MFMA(h1, bh1, acc); am = MFMA(h1, bl1, am); am = MFMA(l1, bh1, am); \
            floatx4 v; \
            _Pragma("unroll") \
            for (int r = 0; r < 4; ++r) { \
                float t = fmaf(am[r], INV2048, acc[r]); \
                v[r] = (RELU) ? fmaxf(t, 0.0f) : t; \
            } \
            st_split(AHw, ALw, wrA + nt * 16, v); \
        } \
    } while (0)

    RD_A(); UNIT64(EB_B1, ws + WS_BST + 0,   true);
    RD_A(); UNIT64(EB_B2, ws + WS_BST + 64,  true);

    // ---- a0: h-part (K=64) + q-part (K=32) + rank-1 ----
    RD_A();
    {
        const float* za0 = ws + WS_ZA0 + kk * 64;
        const float* w32p = ws + WS_W32 + 64;
#pragma unroll
        for (int nt = 0; nt < 4; ++nt) {
            const float bv = za0[nt * 16 + n];
            const float w32 = w32p[nt * 16 + n];
            floatx4 acc = {bv, bv, bv, bv};
            floatx4 am  = {0.f, 0.f, 0.f, 0.f};
            {
                const int e = EB_A0Q + nt;
                const f16x8 bh = ldB(ws_i, e*2+0, lane);
                const f16x8 bl = ldB(ws_i, e*2+1, lane);
                acc = MFMA(qh0, bh, acc); am = MFMA(qh0, bl, am); am = MFMA(ql0, bh, am);
            }
            {
                const int e0 = EB_A0H + nt * 2;
                const f16x8 bh0 = ldB(ws_i, e0*2+0, lane);
                const f16x8 bl0 = ldB(ws_i, e0*2+1, lane);
                const f16x8 bh1 = ldB(ws_i, e0*2+2, lane);
                const f16x8 bl1 = ldB(ws_i, e0*2+3, lane);
                acc = MFMA(h0, bh0, acc); am = MFMA(h0, bl0, am); am = MFMA(l0, bh0, am);
                acc = MFMA(h1, bh1, acc); am = MFMA(h1, bl1, am); am = MFMA(l1, bh1, am);
            }
            floatx4 v;
#pragma unroll
            for (int r = 0; r < 4; ++r) {
                float t = fmaf(am[r], INV2048, acc[r]);
                t = fmaf(w32, q32v[r], t);
                v[r] = fmaxf(t, 0.0f);
            }
            st_split(AHw, ALw, wrA + nt * 16, v);
        }
    }

    RD_A(); UNIT64(EB_A1, ws + WS_BST + 128, true);
    RD_A(); UNIT64(EB_A2, ws + WS_BST + 192, true);

    // ---- lat (4 ntiles, hi-only, no relu) + shape (5th ntile, full hi/lo -> SIG) ----
    RD_A();
    {
        const float* bias = ws + WS_BST + 256;   // latsh[80]
        // lat: rgb path, f16 precision is plenty (tanh*0.5 contracts; threshold 2e-2 direct)
#pragma unroll
        for (int nt = 0; nt < 4; ++nt) {
            const float bv = bias[nt * 16 + n];
            floatx4 acc = {bv, bv, bv, bv};
            const int e0 = EB_LAT + nt * 2;
            const f16x8 bh0 = ldB(ws_i, e0*2+0, lane);
            const f16x8 bh1 = ldB(ws_i, e0*2+2, lane);
            acc = MFMA(h0, bh0, acc);
            acc = MFMA(h1, bh1, acc);
            st_hi(AHw, wrA + nt * 16, acc);
        }
        // shape: sigma path, keep full hi/lo
        {
            const float bv = bias[64 + n];
            floatx4 acc = {bv, bv, bv, bv};
            floatx4 am  = {0.f, 0.f, 0.f, 0.f};
            const int e0 = EB_LAT + 8;
            const f16x8 bh0 = ldB(ws_i, e0*2+0, lane);
            const f16x8 bl0 = ldB(ws_i, e0*2+1, lane);
            const f16x8 bh1 = ldB(ws_i, e0*2+2, lane);
            const f16x8 bl1 = ldB(ws_i, e0*2+3, lane);
            acc = MFMA(h0, bh0, acc); am = MFMA(h0, bl0, am); am = MFMA(l0, bh0, am);
            acc = MFMA(h1, bh1, acc); am = MFMA(h1, bl1, am); am = MFMA(l1, bh1, am);
            if (n == 0) {
#pragma unroll
                for (int r = 0; r < 4; ++r)
                    SIGw[quad * 4 + r] = fmaf(am[r], INV2048, acc[r]);   // sigma pre-relu
            }
        }
    }

    // ---- c0: 64 -> 16, hi-only, relu, fp32 to CC (CC overlays QH; Q is dead) ----
    h0 = rdfragP(AHw, rdA, sel);
    h1 = rdfragP(AHw, rdA + 32, sel);
    {
        const float* bias = ws + WS_BST + 336;
        const float bv = bias[n];
        floatx4 acc = {bv, bv, bv, bv};
        const f16x8 bh0 = ldB(ws_i, (EB_C0+0)*2+0, lane);
        const f16x8 bh1 = ldB(ws_i, (EB_C0+1)*2+0, lane);
        acc = MFMA(h0, bh0, acc);
        acc = MFMA(h1, bh1, acc);
#pragma unroll
        for (int r = 0; r < 4; ++r)
            CCw[(quad * 4 + r) * 20 + n] = fmaxf(acc[r], 0.0f);
    }

    // ---- heads: lane = p*4 + o ----
    {
        const int p = lane >> 2, o = lane & 3;
        float v;
        if (o < 3) {
            const float* cr = CCw + p * 20;
            float a = b_c1[o];
#pragma unroll
            for (int i = 0; i < 16; ++i) a = fmaf(w_c1[o * 16 + i], cr[i], a);
            v = (tanhf(a) + 1.0f) * 0.5f;
        } else {
            const float sig = SIGw[p];
            const float outs = OUTSw[p];
            v = (outs > 0.5f) ? 0.0f : fmaxf(sig, 0.0f);
        }
        const long idx = (long)kk * PN + p0 + p;
        out[OFF_UNMASK + (idx << 2) + o] = v;
    }
#undef RD_A
#undef UNIT64
}

// ============================ compose pass ============================
__global__ __launch_bounds__(256)
void compose_kernel(float* __restrict__ out) {
    const int p = blockIdx.x * blockDim.x + threadIdx.x;
    const float4* un = (const float4*)(out + OFF_UNMASK);
    float4 u[KSLOTS];
    float s = 0.0f;
#pragma unroll
    for (int k = 0; k < KSLOTS; ++k) {
        u[k] = un[k * PN + p];
        s += u[k].w;
    }
    const float denom = s + 1e-5f;
    float4* mk = (float4*)(out + OFF_MASKED);
    float* ms = out + OFF_MASKS;
    float4 r = make_float4(0.f, 0.f, 0.f, 0.f);
#pragma unroll
    for (int k = 0; k < KSLOTS; ++k) {
        const float m = u[k].w / denom;
        ms[k * PN + p] = m;
        const float4 v = make_float4(u[k].x * m, u[k].y * m, u[k].z * m, u[k].w * m);
        mk[k * PN + p] = v;
        r.x += v.x; r.y += v.y; r.z += v.z; r.w += v.w;
    }
    ((float4*)(out + OFF_RAWS))[p] = r;
}

// ============================ launch ============================
extern "C" void kernel_launch(void* const* d_in, const int* in_sizes, int n_in,
                              void* d_out, int out_size, void* d_ws, size_t ws_size,
                              hipStream_t stream) {
    const float* coor = (const float*)d_in[0];
    const float* z    = (const float*)d_in[1];
    const float* ft   = (const float*)d_in[2];
    const float* pos  = (const float*)d_in[3];
    const float* w_b0 = (const float*)d_in[4];  const float* b_b0 = (const float*)d_in[5];
    const float* w_b1 = (const float*)d_in[6];  const float* b_b1 = (const float*)d_in[7];
    const float* w_b2 = (const float*)d_in[8];  const float* b_b2 = (const float*)d_in[9];
    const float* w_a0 = (const float*)d_in[10]; const float* b_a0 = (const float*)d_in[11];
    const float* w_a1 = (const float*)d_in[12]; const float* b_a1 = (const float*)d_in[13];
    const float* w_a2 = (const float*)d_in[14]; const float* b_a2 = (const float*)d_in[15];
    const float* w_lat = (const float*)d_in[16]; const float* b_lat = (const float*)d_in[17];
    const float* w_sh  = (const float*)d_in[18]; const float* b_sh  = (const float*)d_in[19];
    const float* w_c0  = (const float*)d_in[20]; const float* b_c0  = (const float*)d_in[21];
    const float* w_c1  = (const float*)d_in[22]; const float* b_c1  = (const float*)d_in[23];
    float* out = (float*)d_out;
    float* ws  = (float*)d_ws;

    hipLaunchKernelGGL(prep_kernel, dim3(34), dim3(256), 0, stream,
                       z,
                       w_b0, b_b0, w_b1, b_b1, w_b2, b_b2,
                       w_a0, b_a0, w_a1, b_a1, w_a2, b_a2,
                       w_lat, b_lat, w_sh, b_sh, w_c0, b_c0, ws);
    hipLaunchKernelGGL(fg_kernel, dim3((KSLOTS * PN / 16) / 4), dim3(256), 0, stream,
                       coor, ft, pos, w_c1, b_c1, ws, out);
    hipLaunchKernelGGL(compose_kernel, dim3(PN / 256), dim3(256), 0, stream, out);
}

// Round 8
// 382.478 us; speedup vs baseline: 1.5247x; 1.5247x over previous
//
#include <hip/hip_runtime.h>
#include <math.h>

#define KSLOTS 8
#define PN     131072
#define LOC_RATIO 0.5714285714285714f
#define INV2048 4.8828125e-4f
#define RPS    68     // A-plane row-pair stride (dwords), 16B-aligned; reads are ~4 touches/bank = phase-minimum
#define QST    40     // Q-plane row-pair stride (33 cols used)

typedef _Float16 f16x8 __attribute__((ext_vector_type(8)));
typedef __fp16 pk16x2 __attribute__((ext_vector_type(2)));
typedef float floatx4 __attribute__((ext_vector_type(4)));
union F4H8 { int4 i; f16x8 h; };
union PK2I { pk16x2 h; int i; };

#define MFMA(A_,B_,C_) __builtin_amdgcn_mfma_f32_16x16x32_f16(A_,B_,C_,0,0,0)

// ---- B-fragment pair bases (each pair = bh,bl slots; slot = e*2+term) ----
#define EB_B0   0
#define EB_B1   4
#define EB_B2   12
#define EB_A0Q  20
#define EB_A0H  24
#define EB_A1   32
#define EB_A2   40
#define EB_LAT  48
#define EB_C0   58
// frag region: 60 pairs * 2 slots * 64 lanes * 4 dw = 30720 dwords
#define WS_ZB0  30720   // [8][64] f32
#define WS_ZA0  31232
#define WS_BST  31744   // b1@0 b2@64 a1@128 a2@192 latsh@256(80) c0@336(16)
#define WS_W32  32096   // wb0_col32[64], wa0_col32[64]

// ---- output layout (float offsets) ----
#define OFF_RAWS     0
#define OFF_MASKED   524288
#define OFF_UNMASK   4718592
#define OFF_MASKS    8912896

// ---- per-wave LDS map (dwords) ----
#define L_AH   0      // 544
#define L_AL   544    // 544
#define L_QH   1088   // 320 (CC overlays after a0)
#define L_QL   1408   // 320
#define L_Q32  1728   // 16
#define L_OUTS 1744   // 16
#define L_SIG  1760   // 16
#define L_CC   1088
#define LROW   1776   // 7104 B/wave -> 28416 B/block -> 5 blocks/CU

// ============================ prep kernel ============================
__global__ void prep_kernel(const float* __restrict__ z_slots,
                            const float* __restrict__ w_b0, const float* __restrict__ b_b0,
                            const float* __restrict__ w_b1, const float* __restrict__ b_b1,
                            const float* __restrict__ w_b2, const float* __restrict__ b_b2,
                            const float* __restrict__ w_a0, const float* __restrict__ b_a0,
                            const float* __restrict__ w_a1, const float* __restrict__ b_a1,
                            const float* __restrict__ w_a2, const float* __restrict__ b_a2,
                            const float* __restrict__ w_lat, const float* __restrict__ b_lat,
                            const float* __restrict__ w_sh, const float* __restrict__ b_sh,
                            const float* __restrict__ w_c0, const float* __restrict__ b_c0,
                            float* __restrict__ ws) {
    const int tid = blockIdx.x * blockDim.x + threadIdx.x;
    if (tid < 7680) {
        const int lane = tid & 63;
        const int term = (tid >> 6) & 1;
        const int e    = tid >> 7;         // 0..59
        int u, nt, ks;
        if      (e < 4)  { u = 0; nt = e;            ks = 0; }
        else if (e < 12) { u = 1; nt = (e-4)  >> 1;  ks = (e-4)  & 1; }
        else if (e < 20) { u = 2; nt = (e-12) >> 1;  ks = (e-12) & 1; }
        else if (e < 24) { u = 3; nt = e - 20;       ks = 0; }
        else if (e < 32) { u = 4; nt = (e-24) >> 1;  ks = (e-24) & 1; }
        else if (e < 40) { u = 5; nt = (e-32) >> 1;  ks = (e-32) & 1; }
        else if (e < 48) { u = 6; nt = (e-40) >> 1;  ks = (e-40) & 1; }
        else if (e < 58) { u = 7; nt = (e-48) >> 1;  ks = (e-48) & 1; }
        else             { u = 8; nt = 0;            ks = e - 58; }
        const int jo = nt * 16 + (lane & 15);
        const int quad = lane >> 4;
        f16x8 frag;
#pragma unroll
        for (int j = 0; j < 8; ++j) {
            const int k = ks * 32 + quad * 8 + j;
            float w = 0.0f;
            switch (u) {
                case 0: w = w_b0[jo * 97 + k]; break;          // k<32
                case 1: w = w_b1[jo * 64 + k]; break;
                case 2: w = w_b2[jo * 64 + k]; break;
                case 3: w = w_a0[jo * 161 + k]; break;         // k<32
                case 4: w = w_a0[jo * 161 + 97 + k]; break;
                case 5: w = w_a1[jo * 64 + k]; break;
                case 6: w = w_a2[jo * 64 + k]; break;
                case 7: w = (jo < 64) ? w_lat[jo * 64 + k]
                          : ((jo == 64) ? w_sh[k] : 0.0f); break;
                default: w = w_c0[jo * 64 + k]; break;
            }
            const _Float16 hi = (_Float16)w;
            frag[j] = (term == 0) ? hi : (_Float16)((w - (float)hi) * 2048.0f);
        }
        ((f16x8*)ws)[tid] = frag;
    } else if (tid < 8192) {
        const int idx = tid - 7680;            // 0..511
        const int k = idx >> 6, j = idx & 63;
        float s0 = b_b0[j], s1 = b_a0[j];
        for (int i = 0; i < 64; ++i) {
            const float zv = z_slots[k * 64 + i];
            s0 = fmaf(w_b0[j * 97 + 33 + i], zv, s0);
            s1 = fmaf(w_a0[j * 161 + 33 + i], zv, s1);
        }
        ws[WS_ZB0 + idx] = s0;
        ws[WS_ZA0 + idx] = s1;
    } else if (tid < 8544) {
        const int idx = tid - 8192;            // 0..351
        float v;
        if      (idx < 64)  v = b_b1[idx];
        else if (idx < 128) v = b_b2[idx - 64];
        else if (idx < 192) v = b_a1[idx - 128];
        else if (idx < 256) v = b_a2[idx - 192];
        else if (idx < 336) { const int j = idx - 256; v = (j < 64) ? b_lat[j] : ((j == 64) ? b_sh[0] : 0.0f); }
        else                v = b_c0[idx - 336];
        ws[WS_BST + idx] = v;
    } else if (tid < 8672) {
        const int idx = tid - 8544;            // 0..127
        const int j = idx & 63;
        ws[WS_W32 + idx] = (idx < 64) ? w_b0[j * 97 + 32] : w_a0[j * 161 + 32];
    }
}

// ============================ device helpers ============================
__device__ __forceinline__ f16x8 rdfrag(const int* plane, int addr, unsigned sel) {
    const int4 a = *(const int4*)(plane + addr);
    const int4 b = *(const int4*)(plane + addr + 4);
    F4H8 u;
    u.i.x = __builtin_amdgcn_perm(a.y, a.x, sel);
    u.i.y = __builtin_amdgcn_perm(a.w, a.z, sel);
    u.i.z = __builtin_amdgcn_perm(b.y, b.x, sel);
    u.i.w = __builtin_amdgcn_perm(b.w, b.z, sel);
    return u.h;
}

__device__ __forceinline__ f16x8 as_h8(int4 v) { F4H8 u; u.i = v; return u.h; }

__device__ __forceinline__ int pkrtz_i(float a, float b) {
    PK2I u;
    u.h = __builtin_amdgcn_cvt_pkrtz(a, b);
    return u.i;
}

__device__ __forceinline__ void st_split(int* AHw, int* ALw, int addr, floatx4 v) {
    const PK2I h01 = { __builtin_amdgcn_cvt_pkrtz(v[0], v[1]) };
    const PK2I h23 = { __builtin_amdgcn_cvt_pkrtz(v[2], v[3]) };
    const float f0 = (float)h01.h.x, f1 = (float)h01.h.y;
    const float f2 = (float)h23.h.x, f3 = (float)h23.h.y;
    AHw[addr]       = h01.i;
    AHw[addr + RPS] = h23.i;
    ALw[addr]       = pkrtz_i((v[0]-f0)*2048.f, (v[1]-f1)*2048.f);
    ALw[addr + RPS] = pkrtz_i((v[2]-f2)*2048.f, (v[3]-f3)*2048.f);
}

__device__ __forceinline__ void st_hi(int* AHw, int addr, floatx4 v) {
    AHw[addr]       = pkrtz_i(v[0], v[1]);
    AHw[addr + RPS] = pkrtz_i(v[2], v[3]);
}

__device__ __forceinline__ void st_pk16(int* QHw, int* QLw, int rp, int halfsel, int feat, float v) {
    const _Float16 h = (_Float16)v;
    const float hf = (float)h;
    const _Float16 l = (_Float16)((v - hf) * 2048.0f);
    ((unsigned short*)QHw)[(rp * QST + feat) * 2 + halfsel] = __builtin_bit_cast(unsigned short, h);
    ((unsigned short*)QLw)[(rp * QST + feat) * 2 + halfsel] = __builtin_bit_cast(unsigned short, l);
}

// 64->64 hidden unit; B-fragment loads batched ahead of MFMA use for VMEM ILP
__device__ __forceinline__ void unit64(int* AHw, int* ALw, const int* ws_i, int ebase,
                                       const float* __restrict__ bias, bool relu,
                                       f16x8 h0, f16x8 l0, f16x8 h1, f16x8 l1,
                                       int lane, int n, int wrA) {
    const int4* Bp = (const int4*)ws_i;
    int4 B[8];
    floatx4 acc[4], am[4];
    // k0 half: load 8 frags, then MFMA
#pragma unroll
    for (int nt = 0; nt < 4; ++nt) {
        B[nt*2+0] = Bp[(ebase*2 + nt*4 + 0) * 64 + lane];
        B[nt*2+1] = Bp[(ebase*2 + nt*4 + 1) * 64 + lane];
    }
#pragma unroll
    for (int nt = 0; nt < 4; ++nt) {
        const float bv = bias[nt * 16 + n];
        acc[nt] = (floatx4){bv, bv, bv, bv};
        am[nt]  = (floatx4){0.f, 0.f, 0.f, 0.f};
        acc[nt] = MFMA(h0, as_h8(B[nt*2+0]), acc[nt]);
        am[nt]  = MFMA(h0, as_h8(B[nt*2+1]), am[nt]);
        am[nt]  = MFMA(l0, as_h8(B[nt*2+0]), am[nt]);
    }
    // k1 half
#pragma unroll
    for (int nt = 0; nt < 4; ++nt) {
        B[nt*2+0] = Bp[(ebase*2 + nt*4 + 2) * 64 + lane];
        B[nt*2+1] = Bp[(ebase*2 + nt*4 + 3) * 64 + lane];
    }
#pragma unroll
    for (int nt = 0; nt < 4; ++nt) {
        acc[nt] = MFMA(h1, as_h8(B[nt*2+0]), acc[nt]);
        am[nt]  = MFMA(h1, as_h8(B[nt*2+1]), am[nt]);
        am[nt]  = MFMA(l1, as_h8(B[nt*2+0]), am[nt]);
    }
#pragma unroll
    for (int nt = 0; nt < 4; ++nt) {
        floatx4 v;
#pragma unroll
        for (int r = 0; r < 4; ++r) {
            float t = fmaf(am[nt][r], INV2048, acc[nt][r]);
            v[r] = relu ? fmaxf(t, 0.0f) : t;
        }
        st_split(AHw, ALw, wrA + nt * 16, v);
    }
}

// ============================ main kernel ============================
__global__ __launch_bounds__(256, 5)
void fg_kernel(const float* __restrict__ coor_in,
               const float* __restrict__ fg_transform,
               const float* __restrict__ fg_slot_pos,
               const float* __restrict__ w_c1, const float* __restrict__ b_c1,
               const float* __restrict__ ws,
               float* __restrict__ out) {
    __shared__ int LB[4][LROW];
    const int lane = threadIdx.x & 63;
    const int wv   = threadIdx.x >> 6;
    const int tile = blockIdx.x * 4 + wv;
    const int kk = tile >> 13;            // 8192 tiles per slot
    const int p0 = (tile & 8191) << 4;

    int* AHw = LB[wv] + L_AH;
    int* ALw = LB[wv] + L_AL;
    int* QHw = LB[wv] + L_QH;
    int* QLw = LB[wv] + L_QL;
    float* Q32w  = (float*)(LB[wv] + L_Q32);
    float* OUTSw = (float*)(LB[wv] + L_OUTS);
    float* SIGw  = (float*)(LB[wv] + L_SIG);
    float* CCw   = (float*)(LB[wv] + L_CC);   // overlays QH (Q dead after a0)

    const int* ws_i = (const int*)ws;
    const int4* Bp = (const int4*)ws_i;
    const int n = lane & 15, quad = lane >> 4;
    const unsigned sel = (n & 1) ? 0x07060302u : 0x05040100u;
    const int rdA = (n >> 1) * RPS + quad * 8;
    const int rdQ = (n >> 1) * QST + quad * 8;
    const int wrA = (2 * quad) * RPS + n;

    // ---- phase 0: embedding, non-divergent (role = quad, point = n) ----
    {
        const int p = n;
        const int role = quad;
        const long idx3 = ((long)kk * PN + p0 + p) * 3;
        const float x = coor_in[idx3 + 0];
        const float y = coor_in[idx3 + 1];
        const float zc = coor_in[idx3 + 2];
        const float T00 = fg_transform[0], T01 = fg_transform[1], T02 = fg_transform[2];
        const float T10 = fg_transform[3], T11 = fg_transform[4], T12 = fg_transform[5];
        const float T20 = fg_transform[6], T21 = fg_transform[7], T22 = fg_transform[8];
        if (role < 3) {
            const float px = fg_slot_pos[kk*3+0], py = fg_slot_pos[kk*3+1], pz = fg_slot_pos[kk*3+2];
            const float rx = x - px, ry = y - py, rz = zc - pz;
            const float cx = T00*rx + T01*ry + T02*rz;
            const float cy = T10*rx + T11*ry + T12*rz;
            const float cz = T20*rx + T21*ry + T22*rz;
            const float c = (role == 0) ? cx : ((role == 1) ? cy : cz);
            const int rp = p >> 1;
            const int hs = p & 1;
            st_pk16(QHw, QLw, rp, hs, role, c);
            const float rev = c * 0.15915494309189535f;
            const float fr = rev - floorf(rev);
            float s  = __builtin_amdgcn_sinf(fr);
            float co = __builtin_amdgcn_cosf(fr);
#pragma unroll
            for (int l = 0; l < 5; ++l) {
                st_pk16(QHw, QLw, rp, hs, 3 + 6*l + role, s);
                if (l == 4 && role == 2) {
                    Q32w[p] = co;                       // q[32] = cos(16 z), fp32
                } else {
                    st_pk16(QHw, QLw, rp, hs, 6 + 6*l + role, co);
                }
                if (l < 4) {
                    const float t = s * co;
                    const float s2 = s * s;
                    co = fmaf(-2.0f, s2, 1.0f);
                    s  = t + t;
                }
            }
        } else {
            const float o0 = T00*x + T01*y + T02*zc;
            const float o1 = T10*x + T11*y + T12*zc;
            const float o2 = T20*x + T21*y + T22*zc;
            const bool outs = (fabsf(o0) > LOC_RATIO) || (fabsf(o1) > LOC_RATIO) || (fabsf(o2) > LOC_RATIO);
            OUTSw[p] = outs ? 1.0f : 0.0f;
        }
    }

    // ---- q fragments (K=32, registers, reused by b0 and a0) ----
    const f16x8 qh0 = rdfrag(QHw, rdQ, sel);
    const f16x8 ql0 = rdfrag(QLw, rdQ, sel);
    floatx4 q32v;
#pragma unroll
    for (int r = 0; r < 4; ++r) q32v[r] = Q32w[quad * 4 + r];

    // ---- b0: q(K=32) + rank-1 q32 (loads batched) ----
    {
        const float* zb0 = ws + WS_ZB0 + kk * 64;
        const float* w32p = ws + WS_W32;
        int4 B[8];
#pragma unroll
        for (int nt = 0; nt < 4; ++nt) {
            B[nt*2+0] = Bp[((EB_B0 + nt)*2 + 0) * 64 + lane];
            B[nt*2+1] = Bp[((EB_B0 + nt)*2 + 1) * 64 + lane];
        }
#pragma unroll
        for (int nt = 0; nt < 4; ++nt) {
            const float bv = zb0[nt * 16 + n];
            const float w32 = w32p[nt * 16 + n];
            floatx4 acc = {bv, bv, bv, bv};
            floatx4 am  = {0.f, 0.f, 0.f, 0.f};
            acc = MFMA(qh0, as_h8(B[nt*2+0]), acc);
            am  = MFMA(qh0, as_h8(B[nt*2+1]), am);
            am  = MFMA(ql0, as_h8(B[nt*2+0]), am);
            floatx4 v;
#pragma unroll
            for (int r = 0; r < 4; ++r) {
                float t = fmaf(am[r], INV2048, acc[r]);
                t = fmaf(w32, q32v[r], t);
                v[r] = fmaxf(t, 0.0f);
            }
            st_split(AHw, ALw, wrA + nt * 16, v);
        }
    }

    f16x8 h0, l0, h1, l1;
#define RD_A() do { \
        h0 = rdfrag(AHw, rdA, sel);      l0 = rdfrag(ALw, rdA, sel); \
        h1 = rdfrag(AHw, rdA + 32, sel); l1 = rdfrag(ALw, rdA + 32, sel); \
    } while (0)

    RD_A(); unit64(AHw, ALw, ws_i, EB_B1, ws + WS_BST + 0,   true, h0, l0, h1, l1, lane, n, wrA);
    RD_A(); unit64(AHw, ALw, ws_i, EB_B2, ws + WS_BST + 64,  true, h0, l0, h1, l1, lane, n, wrA);

    // ---- a0: q-part (K=32) + h-part (K=64) + rank-1, loads batched per k-section ----
    RD_A();
    {
        const float* za0 = ws + WS_ZA0 + kk * 64;
        const float* w32p = ws + WS_W32 + 64;
        floatx4 acc[4], am[4];
        int4 B[8];
        // q section
#pragma unroll
        for (int nt = 0; nt < 4; ++nt) {
            B[nt*2+0] = Bp[((EB_A0Q + nt)*2 + 0) * 64 + lane];
            B[nt*2+1] = Bp[((EB_A0Q + nt)*2 + 1) * 64 + lane];
        }
#pragma unroll
        for (int nt = 0; nt < 4; ++nt) {
            const float bv = za0[nt * 16 + n];
            acc[nt] = (floatx4){bv, bv, bv, bv};
            am[nt]  = (floatx4){0.f, 0.f, 0.f, 0.f};
            acc[nt] = MFMA(qh0, as_h8(B[nt*2+0]), acc[nt]);
            am[nt]  = MFMA(qh0, as_h8(B[nt*2+1]), am[nt]);
            am[nt]  = MFMA(ql0, as_h8(B[nt*2+0]), am[nt]);
        }
        // h k0
#pragma unroll
        for (int nt = 0; nt < 4; ++nt) {
            B[nt*2+0] = Bp[((EB_A0H + nt*2)*2 + 0) * 64 + lane];
            B[nt*2+1] = Bp[((EB_A0H + nt*2)*2 + 1) * 64 + lane];
        }
#pragma unroll
        for (int nt = 0; nt < 4; ++nt) {
            acc[nt] = MFMA(h0, as_h8(B[nt*2+0]), acc[nt]);
            am[nt]  = MFMA(h0, as_h8(B[nt*2+1]), am[nt]);
            am[nt]  = MFMA(l0, as_h8(B[nt*2+0]), am[nt]);
        }
        // h k1
#pragma unroll
        for (int nt = 0; nt < 4; ++nt) {
            B[nt*2+0] = Bp[((EB_A0H + nt*2)*2 + 2) * 64 + lane];
            B[nt*2+1] = Bp[((EB_A0H + nt*2)*2 + 3) * 64 + lane];
        }
#pragma unroll
        for (int nt = 0; nt < 4; ++nt) {
            acc[nt] = MFMA(h1, as_h8(B[nt*2+0]), acc[nt]);
            am[nt]  = MFMA(h1, as_h8(B[nt*2+1]), am[nt]);
            am[nt]  = MFMA(l1, as_h8(B[nt*2+0]), am[nt]);
        }
#pragma unroll
        for (int nt = 0; nt < 4; ++nt) {
            const float w32 = w32p[nt * 16 + n];
            floatx4 v;
#pragma unroll
            for (int r = 0; r < 4; ++r) {
                float t = fmaf(am[nt][r], INV2048, acc[nt][r]);
                t = fmaf(w32, q32v[r], t);
                v[r] = fmaxf(t, 0.0f);
            }
            st_split(AHw, ALw, wrA + nt * 16, v);
        }
    }

    RD_A(); unit64(AHw, ALw, ws_i, EB_A1, ws + WS_BST + 128, true, h0, l0, h1, l1, lane, n, wrA);
    RD_A(); unit64(AHw, ALw, ws_i, EB_A2, ws + WS_BST + 192, true, h0, l0, h1, l1, lane, n, wrA);

    // ---- lat (4 ntiles, hi-only, no relu) + shape (5th ntile, full hi/lo -> SIG) ----
    RD_A();
    {
        const float* bias = ws + WS_BST + 256;   // latsh[80]
        int4 B[8];
#pragma unroll
        for (int nt = 0; nt < 4; ++nt) {
            B[nt*2+0] = Bp[((EB_LAT + nt*2)*2 + 0) * 64 + lane];
            B[nt*2+1] = Bp[((EB_LAT + nt*2)*2 + 2) * 64 + lane];
        }
#pragma unroll
        for (int nt = 0; nt < 4; ++nt) {
            const float bv = bias[nt * 16 + n];
            floatx4 acc = {bv, bv, bv, bv};
            acc = MFMA(h0, as_h8(B[nt*2+0]), acc);
            acc = MFMA(h1, as_h8(B[nt*2+1]), acc);
            st_hi(AHw, wrA + nt * 16, acc);
        }
        // shape: sigma path, keep full hi/lo
        {
            const float bv = bias[64 + n];
            floatx4 acc = {bv, bv, bv, bv};
            floatx4 am  = {0.f, 0.f, 0.f, 0.f};
            const int e0 = EB_LAT + 8;
            const f16x8 bh0 = as_h8(Bp[(e0*2+0) * 64 + lane]);
            const f16x8 bl0 = as_h8(Bp[(e0*2+1) * 64 + lane]);
            const f16x8 bh1 = as_h8(Bp[(e0*2+2) * 64 + lane]);
            const f16x8 bl1 = as_h8(Bp[(e0*2+3) * 64 + lane]);
            acc = MFMA(h0, bh0, acc); am = MFMA(h0, bl0, am); am = MFMA(l0, bh0, am);
            acc = MFMA(h1, bh1, acc); am = MFMA(h1, bl1, am); am = MFMA(l1, bh1, am);
            if (n == 0) {
#pragma unroll
                for (int r = 0; r < 4; ++r)
                    SIGw[quad * 4 + r] = fmaf(am[r], INV2048, acc[r]);   // sigma pre-relu
            }
        }
    }

    // ---- c0: 64 -> 16, hi-only, relu, fp32 to CC (CC overlays QH; Q is dead) ----
    h0 = rdfrag(AHw, rdA, sel);
    h1 = rdfrag(AHw, rdA + 32, sel);
    {
        const float* bias = ws + WS_BST + 336;
        const float bv = bias[n];
        floatx4 acc = {bv, bv, bv, bv};
        const f16x8 bh0 = as_h8(Bp[((EB_C0+0)*2+0) * 64 + lane]);
        const f16x8 bh1 = as_h8(Bp[((EB_C0+1)*2+0) * 64 + lane]);
        acc = MFMA(h0, bh0, acc);
        acc = MFMA(h1, bh1, acc);
#pragma unroll
        for (int r = 0; r < 4; ++r)
            CCw[(quad * 4 + r) * 20 + n] = fmaxf(acc[r], 0.0f);
    }

    // ---- heads: lane = p*4 + o ----
    {
        const int p = lane >> 2, o = lane & 3;
        float v;
        if (o < 3) {
            const float* cr = CCw + p * 20;
            float a = b_c1[o];
#pragma unroll
            for (int i = 0; i < 16; ++i) a = fmaf(w_c1[o * 16 + i], cr[i], a);
            v = (tanhf(a) + 1.0f) * 0.5f;
        } else {
            const float sig = SIGw[p];
            const float outs = OUTSw[p];
            v = (outs > 0.5f) ? 0.0f : fmaxf(sig, 0.0f);
        }
        const long idx = (long)kk * PN + p0 + p;
        out[OFF_UNMASK + (idx << 2) + o] = v;
    }
#undef RD_A
}

// ============================ compose pass ============================
__global__ __launch_bounds__(256)
void compose_kernel(float* __restrict__ out) {
    const int p = blockIdx.x * blockDim.x + threadIdx.x;
    const float4* un = (const float4*)(out + OFF_UNMASK);
    float4 u[KSLOTS];
    float s = 0.0f;
#pragma unroll
    for (int k = 0; k < KSLOTS; ++k) {
        u[k] = un[k * PN + p];
        s += u[k].w;
    }
    const float denom = s + 1e-5f;
    float4* mk = (float4*)(out + OFF_MASKED);
    float* ms = out + OFF_MASKS;
    float4 r = make_float4(0.f, 0.f, 0.f, 0.f);
#pragma unroll
    for (int k = 0; k < KSLOTS; ++k) {
        const float m = u[k].w / denom;
        ms[k * PN + p] = m;
        const float4 v = make_float4(u[k].x * m, u[k].y * m, u[k].z * m, u[k].w * m);
        mk[k * PN + p] = v;
        r.x += v.x; r.y += v.y; r.z += v.z; r.w += v.w;
    }
    ((float4*)(out + OFF_RAWS))[p] = r;
}

// ============================ launch ============================
extern "C" void kernel_launch(void* const* d_in, const int* in_sizes, int n_in,
                              void* d_out, int out_size, void* d_ws, size_t ws_size,
                              hipStream_t stream) {
    const float* coor = (const float*)d_in[0];
    const float* z    = (const float*)d_in[1];
    const float* ft   = (const float*)d_in[2];
    const float* pos  = (const float*)d_in[3];
    const float* w_b0 = (const float*)d_in[4];  const float* b_b0 = (const float*)d_in[5];
    const float* w_b1 = (const float*)d_in[6];  const float* b_b1 = (const float*)d_in[7];
    const float* w_b2 = (const float*)d_in[8];  const float* b_b2 = (const float*)d_in[9];
    const float* w_a0 = (const float*)d_in[10]; const float* b_a0 = (const float*)d_in[11];
    const float* w_a1 = (const float*)d_in[12]; const float* b_a1 = (const float*)d_in[13];
    const float* w_a2 = (const float*)d_in[14]; const float* b_a2 = (const float*)d_in[15];
    const float* w_lat = (const float*)d_in[16]; const float* b_lat = (const float*)d_in[17];
    const float* w_sh  = (const float*)d_in[18]; const float* b_sh  = (const float*)d_in[19];
    const float* w_c0  = (const float*)d_in[20]; const float* b_c0  = (const float*)d_in[21];
    const float* w_c1  = (const float*)d_in[22]; const float* b_c1  = (const float*)d_in[23];
    float* out = (float*)d_out;
    float* ws  = (float*)d_ws;

    hipLaunchKernelGGL(prep_kernel, dim3(34), dim3(256), 0, stream,
                       z,
                       w_b0, b_b0, w_b1, b_b1, w_b2, b_b2,
                       w_a0, b_a0, w_a1, b_a1, w_a2, b_a2,
                       w_lat, b_lat, w_sh, b_sh, w_c0, b_c0, ws);
    hipLaunchKernelGGL(fg_kernel, dim3((KSLOTS * PN / 16) / 4), dim3(256), 0, stream,
                       coor, ft, pos, w_c1, b_c1, ws, out);
    hipLaunchKernelGGL(compose_kernel, dim3(PN / 256), dim3(256), 0, stream, out);
}

// Round 9
// 335.116 us; speedup vs baseline: 1.7401x; 1.1413x over previous
//
#include <hip/hip_runtime.h>
#include <math.h>

#define KSLOTS 8
#define PN     131072
#define LOC_RATIO 0.5714285714285714f
#define INV2048 4.8828125e-4f
#define RPS    68     // A-plane row-pair stride (dwords)
#define QST    40     // Q-plane row-pair stride

typedef _Float16 f16x8 __attribute__((ext_vector_type(8)));
typedef __fp16 pk16x2 __attribute__((ext_vector_type(2)));
typedef float floatx4 __attribute__((ext_vector_type(4)));
union F4H8 { int4 i; f16x8 h; };
union PK2I { pk16x2 h; int i; };

#define MFMA(A_,B_,C_) __builtin_amdgcn_mfma_f32_16x16x32_f16(A_,B_,C_,0,0,0)

// ---- B-fragment pair bases ----
#define EB_B0   0
#define EB_B1   4
#define EB_B2   12
#define EB_A0Q  20
#define EB_A0H  24
#define EB_A1   32
#define EB_A2   40
#define EB_LAT  48
#define EB_C0   58
#define WS_ZB0  30720
#define WS_ZA0  31232
#define WS_BST  31744   // b1@0 b2@64 a1@128 a2@192 latsh@256(80) c0@336(16)
#define WS_W32  32096

// ---- output layout (float offsets) ----
#define OFF_RAWS     0
#define OFF_MASKED   524288
#define OFF_UNMASK   4718592
#define OFF_MASKS    8912896

// ---- per-wave LDS map (dwords) ----
// A planes (2 tiles): AH0 0, AL0 544, AH1 1088, AL1 1632  (2176 total)
// Q overlay (pre-b0): QH0 0, QL0 320, QH1 640, QL1 960
// CC overlay (post-shape): CC0 at AL0 (544), CC1 at AL1 (1632), 320 dw each
// scratch: Q32 2176 (32), OUTS 2208 (32), SIG 2240 (32)
#define L_AH0  0
#define L_AL0  544
#define L_AH1  1088
#define L_AL1  1632
#define L_Q32  2176
#define L_OUTS 2208
#define L_SIG  2240
#define LROW   2272   // 9088 B/wave * 4 = 36352 B/block

// ============================ prep kernel ============================
__global__ void prep_kernel(const float* __restrict__ z_slots,
                            const float* __restrict__ w_b0, const float* __restrict__ b_b0,
                            const float* __restrict__ w_b1, const float* __restrict__ b_b1,
                            const float* __restrict__ w_b2, const float* __restrict__ b_b2,
                            const float* __restrict__ w_a0, const float* __restrict__ b_a0,
                            const float* __restrict__ w_a1, const float* __restrict__ b_a1,
                            const float* __restrict__ w_a2, const float* __restrict__ b_a2,
                            const float* __restrict__ w_lat, const float* __restrict__ b_lat,
                            const float* __restrict__ w_sh, const float* __restrict__ b_sh,
                            const float* __restrict__ w_c0, const float* __restrict__ b_c0,
                            float* __restrict__ ws) {
    const int tid = blockIdx.x * blockDim.x + threadIdx.x;
    if (tid < 7680) {
        const int lane = tid & 63;
        const int term = (tid >> 6) & 1;
        const int e    = tid >> 7;         // 0..59
        int u, nt, ks;
        if      (e < 4)  { u = 0; nt = e;            ks = 0; }
        else if (e < 12) { u = 1; nt = (e-4)  >> 1;  ks = (e-4)  & 1; }
        else if (e < 20) { u = 2; nt = (e-12) >> 1;  ks = (e-12) & 1; }
        else if (e < 24) { u = 3; nt = e - 20;       ks = 0; }
        else if (e < 32) { u = 4; nt = (e-24) >> 1;  ks = (e-24) & 1; }
        else if (e < 40) { u = 5; nt = (e-32) >> 1;  ks = (e-32) & 1; }
        else if (e < 48) { u = 6; nt = (e-40) >> 1;  ks = (e-40) & 1; }
        else if (e < 58) { u = 7; nt = (e-48) >> 1;  ks = (e-48) & 1; }
        else             { u = 8; nt = 0;            ks = e - 58; }
        const int jo = nt * 16 + (lane & 15);
        const int quad = lane >> 4;
        f16x8 frag;
#pragma unroll
        for (int j = 0; j < 8; ++j) {
            const int k = ks * 32 + quad * 8 + j;
            float w = 0.0f;
            switch (u) {
                case 0: w = w_b0[jo * 97 + k]; break;
                case 1: w = w_b1[jo * 64 + k]; break;
                case 2: w = w_b2[jo * 64 + k]; break;
                case 3: w = w_a0[jo * 161 + k]; break;
                case 4: w = w_a0[jo * 161 + 97 + k]; break;
                case 5: w = w_a1[jo * 64 + k]; break;
                case 6: w = w_a2[jo * 64 + k]; break;
                case 7: w = (jo < 64) ? w_lat[jo * 64 + k]
                          : ((jo == 64) ? w_sh[k] : 0.0f); break;
                default: w = w_c0[jo * 64 + k]; break;
            }
            const _Float16 hi = (_Float16)w;
            frag[j] = (term == 0) ? hi : (_Float16)((w - (float)hi) * 2048.0f);
        }
        ((f16x8*)ws)[tid] = frag;
    } else if (tid < 8192) {
        const int idx = tid - 7680;
        const int k = idx >> 6, j = idx & 63;
        float s0 = b_b0[j], s1 = b_a0[j];
        for (int i = 0; i < 64; ++i) {
            const float zv = z_slots[k * 64 + i];
            s0 = fmaf(w_b0[j * 97 + 33 + i], zv, s0);
            s1 = fmaf(w_a0[j * 161 + 33 + i], zv, s1);
        }
        ws[WS_ZB0 + idx] = s0;
        ws[WS_ZA0 + idx] = s1;
    } else if (tid < 8544) {
        const int idx = tid - 8192;
        float v;
        if      (idx < 64)  v = b_b1[idx];
        else if (idx < 128) v = b_b2[idx - 64];
        else if (idx < 192) v = b_a1[idx - 128];
        else if (idx < 256) v = b_a2[idx - 192];
        else if (idx < 336) { const int j = idx - 256; v = (j < 64) ? b_lat[j] : ((j == 64) ? b_sh[0] : 0.0f); }
        else                v = b_c0[idx - 336];
        ws[WS_BST + idx] = v;
    } else if (tid < 8672) {
        const int idx = tid - 8544;
        const int j = idx & 63;
        ws[WS_W32 + idx] = (idx < 64) ? w_b0[j * 97 + 32] : w_a0[j * 161 + 32];
    }
}

// ============================ device helpers ============================
__device__ __forceinline__ f16x8 rdfrag(const int* plane, int addr, unsigned sel) {
    const int4 a = *(const int4*)(plane + addr);
    const int4 b = *(const int4*)(plane + addr + 4);
    F4H8 u;
    u.i.x = __builtin_amdgcn_perm(a.y, a.x, sel);
    u.i.y = __builtin_amdgcn_perm(a.w, a.z, sel);
    u.i.z = __builtin_amdgcn_perm(b.y, b.x, sel);
    u.i.w = __builtin_amdgcn_perm(b.w, b.z, sel);
    return u.h;
}

__device__ __forceinline__ f16x8 as_h8(int4 v) { F4H8 u; u.i = v; return u.h; }

__device__ __forceinline__ int pkrtz_i(float a, float b) {
    PK2I u;
    u.h = __builtin_amdgcn_cvt_pkrtz(a, b);
    return u.i;
}

__device__ __forceinline__ void st_split(int* AHw, int* ALw, int addr, floatx4 v) {
    const PK2I h01 = { __builtin_amdgcn_cvt_pkrtz(v[0], v[1]) };
    const PK2I h23 = { __builtin_amdgcn_cvt_pkrtz(v[2], v[3]) };
    const float f0 = (float)h01.h.x, f1 = (float)h01.h.y;
    const float f2 = (float)h23.h.x, f3 = (float)h23.h.y;
    AHw[addr]       = h01.i;
    AHw[addr + RPS] = h23.i;
    ALw[addr]       = pkrtz_i((v[0]-f0)*2048.f, (v[1]-f1)*2048.f);
    ALw[addr + RPS] = pkrtz_i((v[2]-f2)*2048.f, (v[3]-f3)*2048.f);
}

__device__ __forceinline__ void st_hi(int* AHw, int addr, floatx4 v) {
    AHw[addr]       = pkrtz_i(v[0], v[1]);
    AHw[addr + RPS] = pkrtz_i(v[2], v[3]);
}

__device__ __forceinline__ void st_pk16(int* QHw, int* QLw, int rp, int halfsel, int feat, float v) {
    const _Float16 h = (_Float16)v;
    const float hf = (float)h;
    const _Float16 l = (_Float16)((v - hf) * 2048.0f);
    ((unsigned short*)QHw)[(rp * QST + feat) * 2 + halfsel] = __builtin_bit_cast(unsigned short, h);
    ((unsigned short*)QLw)[(rp * QST + feat) * 2 + halfsel] = __builtin_bit_cast(unsigned short, l);
}

// dual-tile 64->64 hidden unit: B loaded once, applied to both tiles
__device__ __forceinline__ void unitDual(int* AH0, int* AL0, int* AH1, int* AL1,
                                         const int4* Bp, int ebase,
                                         const float* __restrict__ bias,
                                         f16x8 th0, f16x8 tl0, f16x8 th1, f16x8 tl1,
                                         f16x8 uh0, f16x8 ul0, f16x8 uh1, f16x8 ul1,
                                         int lane, int n, int wrA) {
    int4 B[8];
    floatx4 ac0[4], am0[4], ac1[4], am1[4];
    // k0 half
#pragma unroll
    for (int nt = 0; nt < 4; ++nt) {
        B[nt*2+0] = Bp[((ebase + nt*2)*2 + 0) * 64 + lane];
        B[nt*2+1] = Bp[((ebase + nt*2)*2 + 1) * 64 + lane];
    }
#pragma unroll
    for (int nt = 0; nt < 4; ++nt) {
        const float bv = bias[nt * 16 + n];
        const f16x8 bh = as_h8(B[nt*2+0]), bl = as_h8(B[nt*2+1]);
        ac0[nt] = (floatx4){bv, bv, bv, bv};
        am0[nt] = (floatx4){0.f, 0.f, 0.f, 0.f};
        ac1[nt] = (floatx4){bv, bv, bv, bv};
        am1[nt] = (floatx4){0.f, 0.f, 0.f, 0.f};
        ac0[nt] = MFMA(th0, bh, ac0[nt]); am0[nt] = MFMA(th0, bl, am0[nt]); am0[nt] = MFMA(tl0, bh, am0[nt]);
        ac1[nt] = MFMA(uh0, bh, ac1[nt]); am1[nt] = MFMA(uh0, bl, am1[nt]); am1[nt] = MFMA(ul0, bh, am1[nt]);
    }
    // k1 half
#pragma unroll
    for (int nt = 0; nt < 4; ++nt) {
        B[nt*2+0] = Bp[((ebase + nt*2)*2 + 2) * 64 + lane];
        B[nt*2+1] = Bp[((ebase + nt*2)*2 + 3) * 64 + lane];
    }
#pragma unroll
    for (int nt = 0; nt < 4; ++nt) {
        const f16x8 bh = as_h8(B[nt*2+0]), bl = as_h8(B[nt*2+1]);
        ac0[nt] = MFMA(th1, bh, ac0[nt]); am0[nt] = MFMA(th1, bl, am0[nt]); am0[nt] = MFMA(tl1, bh, am0[nt]);
        ac1[nt] = MFMA(uh1, bh, ac1[nt]); am1[nt] = MFMA(uh1, bl, am1[nt]); am1[nt] = MFMA(ul1, bh, am1[nt]);
    }
#pragma unroll
    for (int nt = 0; nt < 4; ++nt) {
        floatx4 v0, v1;
#pragma unroll
        for (int r = 0; r < 4; ++r) {
            v0[r] = fmaxf(fmaf(am0[nt][r], INV2048, ac0[nt][r]), 0.0f);
            v1[r] = fmaxf(fmaf(am1[nt][r], INV2048, ac1[nt][r]), 0.0f);
        }
        st_split(AH0, AL0, wrA + nt * 16, v0);
        st_split(AH1, AL1, wrA + nt * 16, v1);
    }
}

// ============================ main kernel ============================
__global__ __launch_bounds__(256, 3)
void fg_kernel(const float* __restrict__ coor_in,
               const float* __restrict__ fg_transform,
               const float* __restrict__ fg_slot_pos,
               const float* __restrict__ w_c1, const float* __restrict__ b_c1,
               const float* __restrict__ ws,
               float* __restrict__ out) {
    __shared__ int LB[4][LROW];
    const int lane = threadIdx.x & 63;
    const int wv   = threadIdx.x >> 6;
    const int tile = blockIdx.x * 4 + wv;     // 32 points per tile
    const int kk = tile >> 12;                // 4096 tiles per slot
    const int p0 = (tile & 4095) << 5;

    int* AH0 = LB[wv] + L_AH0;
    int* AL0 = LB[wv] + L_AL0;
    int* AH1 = LB[wv] + L_AH1;
    int* AL1 = LB[wv] + L_AL1;
    float* Q32w  = (float*)(LB[wv] + L_Q32);
    float* OUTSw = (float*)(LB[wv] + L_OUTS);
    float* SIGw  = (float*)(LB[wv] + L_SIG);
    float* CC0   = (float*)(LB[wv] + L_AL0);   // overlays AL0 (lo dead after shape)
    float* CC1   = (float*)(LB[wv] + L_AL1);

    const int* ws_i = (const int*)ws;
    const int4* Bp = (const int4*)ws_i;
    const int n = lane & 15, quad = lane >> 4;
    const unsigned sel = (n & 1) ? 0x07060302u : 0x05040100u;
    const int rdA = (n >> 1) * RPS + quad * 8;
    const int rdQ = (n >> 1) * QST + quad * 8;
    const int wrA = (2 * quad) * RPS + n;

    // ---- phase 0: embedding for both tiles (role = quad, point = n) ----
#pragma unroll
    for (int t = 0; t < 2; ++t) {
        int* QHt = LB[wv] + t * 640;
        int* QLt = LB[wv] + t * 640 + 320;
        const int p = n;
        const int role = quad;
        const long idx3 = ((long)kk * PN + p0 + t * 16 + p) * 3;
        const float x = coor_in[idx3 + 0];
        const float y = coor_in[idx3 + 1];
        const float zc = coor_in[idx3 + 2];
        const float T00 = fg_transform[0], T01 = fg_transform[1], T02 = fg_transform[2];
        const float T10 = fg_transform[3], T11 = fg_transform[4], T12 = fg_transform[5];
        const float T20 = fg_transform[6], T21 = fg_transform[7], T22 = fg_transform[8];
        if (role < 3) {
            const float px = fg_slot_pos[kk*3+0], py = fg_slot_pos[kk*3+1], pz = fg_slot_pos[kk*3+2];
            const float rx = x - px, ry = y - py, rz = zc - pz;
            const float cx = T00*rx + T01*ry + T02*rz;
            const float cy = T10*rx + T11*ry + T12*rz;
            const float cz = T20*rx + T21*ry + T22*rz;
            const float c = (role == 0) ? cx : ((role == 1) ? cy : cz);
            const int rp = p >> 1;
            const int hs = p & 1;
            st_pk16(QHt, QLt, rp, hs, role, c);
            const float rev = c * 0.15915494309189535f;
            const float fr = rev - floorf(rev);
            float s  = __builtin_amdgcn_sinf(fr);
            float co = __builtin_amdgcn_cosf(fr);
#pragma unroll
            for (int l = 0; l < 5; ++l) {
                st_pk16(QHt, QLt, rp, hs, 3 + 6*l + role, s);
                if (l == 4 && role == 2) {
                    Q32w[t * 16 + p] = co;
                } else {
                    st_pk16(QHt, QLt, rp, hs, 6 + 6*l + role, co);
                }
                if (l < 4) {
                    const float tt = s * co;
                    const float s2 = s * s;
                    co = fmaf(-2.0f, s2, 1.0f);
                    s  = tt + tt;
                }
            }
        } else {
            const float o0 = T00*x + T01*y + T02*zc;
            const float o1 = T10*x + T11*y + T12*zc;
            const float o2 = T20*x + T21*y + T22*zc;
            const bool outs = (fabsf(o0) > LOC_RATIO) || (fabsf(o1) > LOC_RATIO) || (fabsf(o2) > LOC_RATIO);
            OUTSw[t * 16 + p] = outs ? 1.0f : 0.0f;
        }
    }

    // ---- q fragments for both tiles -> registers (Q planes die at b0 write) ----
    const f16x8 qh_0 = rdfrag(LB[wv] + 0,         rdQ, sel);
    const f16x8 ql_0 = rdfrag(LB[wv] + 320,       rdQ, sel);
    const f16x8 qh_1 = rdfrag(LB[wv] + 640,       rdQ, sel);
    const f16x8 ql_1 = rdfrag(LB[wv] + 960,       rdQ, sel);

    // ---- b0: q(K=32) + rank-1 q32, both tiles ----
    {
        const float* zb0 = ws + WS_ZB0 + kk * 64;
        const float* w32p = ws + WS_W32;
        int4 B[8];
#pragma unroll
        for (int nt = 0; nt < 4; ++nt) {
            B[nt*2+0] = Bp[((EB_B0 + nt)*2 + 0) * 64 + lane];
            B[nt*2+1] = Bp[((EB_B0 + nt)*2 + 1) * 64 + lane];
        }
#pragma unroll
        for (int nt = 0; nt < 4; ++nt) {
            const float bv = zb0[nt * 16 + n];
            const float w32 = w32p[nt * 16 + n];
            const f16x8 bh = as_h8(B[nt*2+0]), bl = as_h8(B[nt*2+1]);
            floatx4 ac0 = {bv, bv, bv, bv}, am0 = {0.f, 0.f, 0.f, 0.f};
            floatx4 ac1 = {bv, bv, bv, bv}, am1 = {0.f, 0.f, 0.f, 0.f};
            ac0 = MFMA(qh_0, bh, ac0); am0 = MFMA(qh_0, bl, am0); am0 = MFMA(ql_0, bh, am0);
            ac1 = MFMA(qh_1, bh, ac1); am1 = MFMA(qh_1, bl, am1); am1 = MFMA(ql_1, bh, am1);
            floatx4 v0, v1;
#pragma unroll
            for (int r = 0; r < 4; ++r) {
                v0[r] = fmaxf(fmaf(w32, Q32w[quad*4+r],      fmaf(am0[r], INV2048, ac0[r])), 0.0f);
                v1[r] = fmaxf(fmaf(w32, Q32w[16+quad*4+r],   fmaf(am1[r], INV2048, ac1[r])), 0.0f);
            }
            st_split(AH0, AL0, wrA + nt * 16, v0);
            st_split(AH1, AL1, wrA + nt * 16, v1);
        }
    }

    f16x8 th0, tl0, th1, tl1, uh0, ul0, uh1, ul1;
#define RD_A2() do { \
        th0 = rdfrag(AH0, rdA, sel);      tl0 = rdfrag(AL0, rdA, sel); \
        th1 = rdfrag(AH0, rdA + 32, sel); tl1 = rdfrag(AL0, rdA + 32, sel); \
        uh0 = rdfrag(AH1, rdA, sel);      ul0 = rdfrag(AL1, rdA, sel); \
        uh1 = rdfrag(AH1, rdA + 32, sel); ul1 = rdfrag(AL1, rdA + 32, sel); \
    } while (0)

    RD_A2(); unitDual(AH0, AL0, AH1, AL1, Bp, EB_B1, ws + WS_BST + 0,   th0, tl0, th1, tl1, uh0, ul0, uh1, ul1, lane, n, wrA);
    RD_A2(); unitDual(AH0, AL0, AH1, AL1, Bp, EB_B2, ws + WS_BST + 64,  th0, tl0, th1, tl1, uh0, ul0, uh1, ul1, lane, n, wrA);

    // ---- a0: q-part (K=32) + h-part (K=64) + rank-1, both tiles ----
    RD_A2();
    {
        const float* za0 = ws + WS_ZA0 + kk * 64;
        const float* w32p = ws + WS_W32 + 64;
        floatx4 ac0[4], am0[4], ac1[4], am1[4];
        int4 B[8];
#pragma unroll
        for (int nt = 0; nt < 4; ++nt) {
            B[nt*2+0] = Bp[((EB_A0Q + nt)*2 + 0) * 64 + lane];
            B[nt*2+1] = Bp[((EB_A0Q + nt)*2 + 1) * 64 + lane];
        }
#pragma unroll
        for (int nt = 0; nt < 4; ++nt) {
            const float bv = za0[nt * 16 + n];
            const f16x8 bh = as_h8(B[nt*2+0]), bl = as_h8(B[nt*2+1]);
            ac0[nt] = (floatx4){bv, bv, bv, bv}; am0[nt] = (floatx4){0.f, 0.f, 0.f, 0.f};
            ac1[nt] = (floatx4){bv, bv, bv, bv}; am1[nt] = (floatx4){0.f, 0.f, 0.f, 0.f};
            ac0[nt] = MFMA(qh_0, bh, ac0[nt]); am0[nt] = MFMA(qh_0, bl, am0[nt]); am0[nt] = MFMA(ql_0, bh, am0[nt]);
            ac1[nt] = MFMA(qh_1, bh, ac1[nt]); am1[nt] = MFMA(qh_1, bl, am1[nt]); am1[nt] = MFMA(ql_1, bh, am1[nt]);
        }
#pragma unroll
        for (int nt = 0; nt < 4; ++nt) {
            B[nt*2+0] = Bp[((EB_A0H + nt*2)*2 + 0) * 64 + lane];
            B[nt*2+1] = Bp[((EB_A0H + nt*2)*2 + 1) * 64 + lane];
        }
#pragma unroll
        for (int nt = 0; nt < 4; ++nt) {
            const f16x8 bh = as_h8(B[nt*2+0]), bl = as_h8(B[nt*2+1]);
            ac0[nt] = MFMA(th0, bh, ac0[nt]); am0[nt] = MFMA(th0, bl, am0[nt]); am0[nt] = MFMA(tl0, bh, am0[nt]);
            ac1[nt] = MFMA(uh0, bh, ac1[nt]); am1[nt] = MFMA(uh0, bl, am1[nt]); am1[nt] = MFMA(ul0, bh, am1[nt]);
        }
#pragma unroll
        for (int nt = 0; nt < 4; ++nt) {
            B[nt*2+0] = Bp[((EB_A0H + nt*2)*2 + 2) * 64 + lane];
            B[nt*2+1] = Bp[((EB_A0H + nt*2)*2 + 3) * 64 + lane];
        }
#pragma unroll
        for (int nt = 0; nt < 4; ++nt) {
            const f16x8 bh = as_h8(B[nt*2+0]), bl = as_h8(B[nt*2+1]);
            ac0[nt] = MFMA(th1, bh, ac0[nt]); am0[nt] = MFMA(th1, bl, am0[nt]); am0[nt] = MFMA(tl1, bh, am0[nt]);
            ac1[nt] = MFMA(uh1, bh, ac1[nt]); am1[nt] = MFMA(uh1, bl, am1[nt]); am1[nt] = MFMA(ul1, bh, am1[nt]);
        }
#pragma unroll
        for (int nt = 0; nt < 4; ++nt) {
            const float w32 = w32p[nt * 16 + n];
            floatx4 v0, v1;
#pragma unroll
            for (int r = 0; r < 4; ++r) {
                v0[r] = fmaxf(fmaf(w32, Q32w[quad*4+r],    fmaf(am0[nt][r], INV2048, ac0[nt][r])), 0.0f);
                v1[r] = fmaxf(fmaf(w32, Q32w[16+quad*4+r], fmaf(am1[nt][r], INV2048, ac1[nt][r])), 0.0f);
            }
            st_split(AH0, AL0, wrA + nt * 16, v0);
            st_split(AH1, AL1, wrA + nt * 16, v1);
        }
    }

    RD_A2(); unitDual(AH0, AL0, AH1, AL1, Bp, EB_A1, ws + WS_BST + 128, th0, tl0, th1, tl1, uh0, ul0, uh1, ul1, lane, n, wrA);
    RD_A2(); unitDual(AH0, AL0, AH1, AL1, Bp, EB_A2, ws + WS_BST + 192, th0, tl0, th1, tl1, uh0, ul0, uh1, ul1, lane, n, wrA);

    // ---- lat (hi-only, no relu) + shape (full hi/lo -> SIG), both tiles ----
    RD_A2();
    {
        const float* bias = ws + WS_BST + 256;   // latsh[80]
        int4 B[8];
#pragma unroll
        for (int nt = 0; nt < 4; ++nt) {
            B[nt*2+0] = Bp[((EB_LAT + nt*2)*2 + 0) * 64 + lane];
            B[nt*2+1] = Bp[((EB_LAT + nt*2)*2 + 2) * 64 + lane];
        }
#pragma unroll
        for (int nt = 0; nt < 4; ++nt) {
            const float bv = bias[nt * 16 + n];
            const f16x8 bh0 = as_h8(B[nt*2+0]), bh1 = as_h8(B[nt*2+1]);
            floatx4 a0 = {bv, bv, bv, bv}, a1 = {bv, bv, bv, bv};
            a0 = MFMA(th0, bh0, a0); a0 = MFMA(th1, bh1, a0);
            a1 = MFMA(uh0, bh0, a1); a1 = MFMA(uh1, bh1, a1);
            st_hi(AH0, wrA + nt * 16, a0);
            st_hi(AH1, wrA + nt * 16, a1);
        }
        // shape (sigma) — full precision
        {
            const float bv = bias[64 + n];
            const int e0 = EB_LAT + 8;
            const f16x8 bh0 = as_h8(Bp[(e0*2+0) * 64 + lane]);
            const f16x8 bl0 = as_h8(Bp[(e0*2+1) * 64 + lane]);
            const f16x8 bh1 = as_h8(Bp[(e0*2+2) * 64 + lane]);
            const f16x8 bl1 = as_h8(Bp[(e0*2+3) * 64 + lane]);
            floatx4 a0 = {bv, bv, bv, bv}, m0 = {0.f, 0.f, 0.f, 0.f};
            floatx4 a1 = {bv, bv, bv, bv}, m1 = {0.f, 0.f, 0.f, 0.f};
            a0 = MFMA(th0, bh0, a0); m0 = MFMA(th0, bl0, m0); m0 = MFMA(tl0, bh0, m0);
            a0 = MFMA(th1, bh1, a0); m0 = MFMA(th1, bl1, m0); m0 = MFMA(tl1, bh1, m0);
            a1 = MFMA(uh0, bh0, a1); m1 = MFMA(uh0, bl0, m1); m1 = MFMA(ul0, bh0, m1);
            a1 = MFMA(uh1, bh1, a1); m1 = MFMA(uh1, bl1, m1); m1 = MFMA(ul1, bh1, m1);
            if (n == 0) {
#pragma unroll
                for (int r = 0; r < 4; ++r) {
                    SIGw[quad * 4 + r]      = fmaf(m0[r], INV2048, a0[r]);
                    SIGw[16 + quad * 4 + r] = fmaf(m1[r], INV2048, a1[r]);
                }
            }
        }
    }

    // ---- c0: 64 -> 16, hi-only, relu; CC overlays AL planes ----
    th0 = rdfrag(AH0, rdA, sel);
    th1 = rdfrag(AH0, rdA + 32, sel);
    uh0 = rdfrag(AH1, rdA, sel);
    uh1 = rdfrag(AH1, rdA + 32, sel);
    {
        const float* bias = ws + WS_BST + 336;
        const float bv = bias[n];
        const f16x8 bh0 = as_h8(Bp[((EB_C0+0)*2+0) * 64 + lane]);
        const f16x8 bh1 = as_h8(Bp[((EB_C0+1)*2+0) * 64 + lane]);
        floatx4 a0 = {bv, bv, bv, bv}, a1 = {bv, bv, bv, bv};
        a0 = MFMA(th0, bh0, a0); a0 = MFMA(th1, bh1, a0);
        a1 = MFMA(uh0, bh0, a1); a1 = MFMA(uh1, bh1, a1);
#pragma unroll
        for (int r = 0; r < 4; ++r) {
            CC0[(quad * 4 + r) * 20 + n] = fmaxf(a0[r], 0.0f);
            CC1[(quad * 4 + r) * 20 + n] = fmaxf(a1[r], 0.0f);
        }
    }

    // ---- heads: lane = p*4 + o, both tiles ----
#pragma unroll
    for (int t = 0; t < 2; ++t) {
        const float* CCt = t ? CC1 : CC0;
        const int p = lane >> 2, o = lane & 3;
        float v;
        if (o < 3) {
            const float* cr = CCt + p * 20;
            float a = b_c1[o];
#pragma unroll
            for (int i = 0; i < 16; ++i) a = fmaf(w_c1[o * 16 + i], cr[i], a);
            v = (tanhf(a) + 1.0f) * 0.5f;
        } else {
            const float sig = SIGw[t * 16 + p];
            const float outs = OUTSw[t * 16 + p];
            v = (outs > 0.5f) ? 0.0f : fmaxf(sig, 0.0f);
        }
        const long idx = (long)kk * PN + p0 + t * 16 + p;
        out[OFF_UNMASK + (idx << 2) + o] = v;
    }
#undef RD_A2
}

// ============================ compose pass ============================
__global__ __launch_bounds__(256)
void compose_kernel(float* __restrict__ out) {
    const int p = blockIdx.x * blockDim.x + threadIdx.x;
    const float4* un = (const float4*)(out + OFF_UNMASK);
    float4 u[KSLOTS];
    float s = 0.0f;
#pragma unroll
    for (int k = 0; k < KSLOTS; ++k) {
        u[k] = un[k * PN + p];
        s += u[k].w;
    }
    const float denom = s + 1e-5f;
    float4* mk = (float4*)(out + OFF_MASKED);
    float* ms = out + OFF_MASKS;
    float4 r = make_float4(0.f, 0.f, 0.f, 0.f);
#pragma unroll
    for (int k = 0; k < KSLOTS; ++k) {
        const float m = u[k].w / denom;
        ms[k * PN + p] = m;
        const float4 v = make_float4(u[k].x * m, u[k].y * m, u[k].z * m, u[k].w * m);
        mk[k * PN + p] = v;
        r.x += v.x; r.y += v.y; r.z += v.z; r.w += v.w;
    }
    ((float4*)(out + OFF_RAWS))[p] = r;
}

// ============================ launch ============================
extern "C" void kernel_launch(void* const* d_in, const int* in_sizes, int n_in,
                              void* d_out, int out_size, void* d_ws, size_t ws_size,
                              hipStream_t stream) {
    const float* coor = (const float*)d_in[0];
    const float* z    = (const float*)d_in[1];
    const float* ft   = (const float*)d_in[2];
    const float* pos  = (const float*)d_in[3];
    const float* w_b0 = (const float*)d_in[4];  const float* b_b0 = (const float*)d_in[5];
    const float* w_b1 = (const float*)d_in[6];  const float* b_b1 = (const float*)d_in[7];
    const float* w_b2 = (const float*)d_in[8];  const float* b_b2 = (const float*)d_in[9];
    const float* w_a0 = (const float*)d_in[10]; const float* b_a0 = (const float*)d_in[11];
    const float* w_a1 = (const float*)d_in[12]; const float* b_a1 = (const float*)d_in[13];
    const float* w_a2 = (const float*)d_in[14]; const float* b_a2 = (const float*)d_in[15];
    const float* w_lat = (const float*)d_in[16]; const float* b_lat = (const float*)d_in[17];
    const float* w_sh  = (const float*)d_in[18]; const float* b_sh  = (const float*)d_in[19];
    const float* w_c0  = (const float*)d_in[20]; const float* b_c0  = (const float*)d_in[21];
    const float* w_c1  = (const float*)d_in[22]; const float* b_c1  = (const float*)d_in[23];
    float* out = (float*)d_out;
    float* ws  = (float*)d_ws;

    hipLaunchKernelGGL(prep_kernel, dim3(34), dim3(256), 0, stream,
                       z,
                       w_b0, b_b0, w_b1, b_b1, w_b2, b_b2,
                       w_a0, b_a0, w_a1, b_a1, w_a2, b_a2,
                       w_lat, b_lat, w_sh, b_sh, w_c0, b_c0, ws);
    hipLaunchKernelGGL(fg_kernel, dim3((KSLOTS * PN / 32) / 4), dim3(256), 0, stream,
                       coor, ft, pos, w_c1, b_c1, ws, out);
    hipLaunchKernelGGL(compose_kernel, dim3(PN / 256), dim3(256), 0, stream, out);
}